// Round 1
// baseline (97.401 us; speedup 1.0000x reference)
//
#include <hip/hip_runtime.h>

// HandGNNEncoder: fused GCN(2->64) + relu + GCN(64->128) + mean-pool.
// Exact algebraic rewrite:
//   y = A_norm @ x            (sparse, 44 nnz, per graph 21x2)
//   z = sum_t wpool[t] * relu(y[t,:] @ W1 + b1)       (length-64 vector)
//   out = z @ W2 + b2                                  (128 outputs)
// where wpool = colsum(A_norm)/21  (mean-pool commuted through layer 2).

namespace {
constexpr float RS2 = 0.70710678118654752f;  // 1/sqrt(2)
constexpr float RS3 = 0.57735026918962576f;  // 1/sqrt(3)
constexpr float RS6 = 0.40824829046386302f;  // 1/sqrt(6)
constexpr float TH  = 1.0f / 3.0f;
constexpr float HF  = 0.5f;

// CSR of A_norm[t,s] (rows t = target node). deg = in-degree + self-loop.
constexpr int ROW_PTR[22] = {0,1,3,5,7,9,11,13,15,17,20,22,24,26,29,31,33,35,38,40,42,44};
constexpr int COL[44] = {
  0,
  0,1,  1,2,  2,3,  3,4,
  0,5,  5,6,  6,7,  7,8,
  0,5,9,   9,10, 10,11, 11,12,
  0,9,13,  13,14, 14,15, 15,16,
  0,13,17, 17,18, 18,19, 19,20
};
constexpr float AW[44] = {
  1.0f,
  RS2,HF,  HF,HF,  HF,HF,  HF,HF,
  RS2,HF,  HF,HF,  HF,HF,  HF,HF,
  RS3,RS6,TH,  RS6,HF,  HF,HF,  HF,HF,
  RS3,TH,TH,   RS6,HF,  HF,HF,  HF,HF,
  RS3,TH,TH,   RS6,HF,  HF,HF,  HF,HF
};
// wpool[s] = (1/21) * sum_t A_norm[t,s]
constexpr float WPOOL[21] = {
  (1.0f + 2.0f*RS2 + 3.0f*RS3)/21.0f,
  1.0f/21.0f, 1.0f/21.0f, 1.0f/21.0f, 0.5f/21.0f,
  (1.0f+RS6)/21.0f,        1.0f/21.0f, 1.0f/21.0f, 0.5f/21.0f,
  (2.0f/3.0f+RS6)/21.0f,   1.0f/21.0f, 1.0f/21.0f, 0.5f/21.0f,
  (2.0f/3.0f+RS6)/21.0f,   1.0f/21.0f, 1.0f/21.0f, 0.5f/21.0f,
  (1.0f/3.0f+RS6)/21.0f,   1.0f/21.0f, 1.0f/21.0f, 0.5f/21.0f
};
} // namespace

// 2 threads per graph: thread owns `half` (64 of the 128 output features).
// 65536 threads = 1024 waves = 1 wave/SIMD over 256 CUs.
__global__ __launch_bounds__(256) void gnn_fused(
    const float* __restrict__ x,   // [G,21,2]
    const float* __restrict__ W1,  // [2,64]
    const float* __restrict__ b1,  // [64]
    const float* __restrict__ W2,  // [64,128]
    const float* __restrict__ b2,  // [128]
    float* __restrict__ out,       // [G,128]
    int G)
{
  __shared__ float sW1[128];
  __shared__ float sb1[64];
  __shared__ float sb2[128];
  __shared__ float sW2[64 * 128];

  const int tid = threadIdx.x;
  for (int i = tid; i < 64 * 128; i += 256) sW2[i] = W2[i];
  if (tid < 128) { sW1[tid] = W1[tid]; sb2[tid] = b2[tid]; }
  if (tid < 64)  { sb1[tid] = b1[tid]; }
  __syncthreads();

  const int gt = blockIdx.x * 256 + tid;
  if (gt >= 2 * G) return;
  const int g    = gt >> 1;
  const int half = gt & 1;

  // ---- front-end: y = A_norm @ x[g]  (sparse, constants fold to literals)
  float y0[21], y1[21];
  {
    float xs0[21], xs1[21];
    const float2* xg = (const float2*)(x + g * 42);
    #pragma unroll
    for (int t = 0; t < 21; ++t) { float2 v = xg[t]; xs0[t] = v.x; xs1[t] = v.y; }
    #pragma unroll
    for (int t = 0; t < 21; ++t) {
      float a0 = 0.f, a1 = 0.f;
      #pragma unroll
      for (int e = ROW_PTR[t]; e < ROW_PTR[t + 1]; ++e) {
        a0 = fmaf(AW[e], xs0[COL[e]], a0);
        a1 = fmaf(AW[e], xs1[COL[e]], a1);
      }
      y0[t] = a0; y1[t] = a1;
    }
  }

  // ---- out accumulators: this thread's 64 contiguous features, init = b2
  float4 acc[16];
  const float4* bb2 = (const float4*)(sb2 + half * 64);
  #pragma unroll
  for (int q = 0; q < 16; ++q) acc[q] = bb2[q];

  // ---- z (64 features) in chunks of 16, immediately folded into out
  for (int c = 0; c < 4; ++c) {
    float z[16];
    #pragma unroll
    for (int j = 0; j < 16; ++j) {
      const int f = c * 16 + j;
      const float u0 = sW1[f];        // W1[0][f] (broadcast LDS read)
      const float u1 = sW1[64 + f];   // W1[1][f]
      const float bv = sb1[f];
      float a = 0.f;
      #pragma unroll
      for (int t = 0; t < 21; ++t) {
        float r = fmaf(y0[t], u0, fmaf(y1[t], u1, bv));
        r = fmaxf(r, 0.f);
        a = fmaf(WPOOL[t], r, a);
      }
      z[j] = a;
    }
    #pragma unroll
    for (int j = 0; j < 16; ++j) {
      const float zf = z[j];
      // 2 distinct wave addresses (half=0/1) -> 2-way LDS aliasing, free.
      const float4* w2row = (const float4*)(sW2 + (c * 16 + j) * 128 + half * 64);
      #pragma unroll
      for (int q = 0; q < 16; ++q) {
        float4 w = w2row[q];
        acc[q].x = fmaf(zf, w.x, acc[q].x);
        acc[q].y = fmaf(zf, w.y, acc[q].y);
        acc[q].z = fmaf(zf, w.z, acc[q].z);
        acc[q].w = fmaf(zf, w.w, acc[q].w);
      }
    }
  }

  float4* op = (float4*)(out + g * 128 + half * 64);
  #pragma unroll
  for (int q = 0; q < 16; ++q) op[q] = acc[q];
}

extern "C" void kernel_launch(void* const* d_in, const int* in_sizes, int n_in,
                              void* d_out, int out_size, void* d_ws, size_t ws_size,
                              hipStream_t stream) {
  const float* x  = (const float*)d_in[0];
  const float* W1 = (const float*)d_in[1];
  const float* b1 = (const float*)d_in[2];
  const float* W2 = (const float*)d_in[3];
  const float* b2 = (const float*)d_in[4];
  float* out = (float*)d_out;

  const int G = in_sizes[0] / 42;          // 21 nodes * 2 coords
  const int threads = 2 * G;
  const int blocks = (threads + 255) / 256;
  hipLaunchKernelGGL(gnn_fused, dim3(blocks), dim3(256), 0, stream,
                     x, W1, b1, W2, b2, out, G);
}

// Round 2
// 78.651 us; speedup vs baseline: 1.2384x; 1.2384x over previous
//
#include <hip/hip_runtime.h>

// HandGNNEncoder: fused GCN(2->64) + relu + GCN(64->128) + mean-pool.
// Exact algebraic rewrite:
//   y = A_norm @ x                                    (sparse, 44 nnz)
//   z = sum_t wpool[t] * relu(y[t,:] @ W1 + b1)       (64-vector / graph)
//   out = z @ W2 + b2                                  (128 / graph)
// Phase 1: VALU computes z (4 thr/graph, 64 graphs/block) -> bf16 in LDS.
// Phase 2: per-wave MFMA 16x16x32_bf16: z[16g x 64k] @ W2[64k x 128n],
//          W2 converted to bf16 + transposed in LDS once per block so
//          B-fragments are contiguous ds_read_b128.

typedef __attribute__((ext_vector_type(8))) short short8;
typedef __attribute__((ext_vector_type(4))) float float4v;

namespace {
constexpr float RS2 = 0.70710678118654752f;
constexpr float RS3 = 0.57735026918962576f;
constexpr float RS6 = 0.40824829046386302f;
constexpr float TH  = 1.0f / 3.0f;
constexpr float HF  = 0.5f;

constexpr int ROW_PTR[22] = {0,1,3,5,7,9,11,13,15,17,20,22,24,26,29,31,33,35,38,40,42,44};
constexpr int COL[44] = {
  0,
  0,1,  1,2,  2,3,  3,4,
  0,5,  5,6,  6,7,  7,8,
  0,5,9,   9,10, 10,11, 11,12,
  0,9,13,  13,14, 14,15, 15,16,
  0,13,17, 17,18, 18,19, 19,20
};
constexpr float AW[44] = {
  1.0f,
  RS2,HF,  HF,HF,  HF,HF,  HF,HF,
  RS2,HF,  HF,HF,  HF,HF,  HF,HF,
  RS3,RS6,TH,  RS6,HF,  HF,HF,  HF,HF,
  RS3,TH,TH,   RS6,HF,  HF,HF,  HF,HF,
  RS3,TH,TH,   RS6,HF,  HF,HF,  HF,HF
};
constexpr float WPOOL[21] = {
  (1.0f + 2.0f*RS2 + 3.0f*RS3)/21.0f,
  1.0f/21.0f, 1.0f/21.0f, 1.0f/21.0f, 0.5f/21.0f,
  (1.0f+RS6)/21.0f,        1.0f/21.0f, 1.0f/21.0f, 0.5f/21.0f,
  (2.0f/3.0f+RS6)/21.0f,   1.0f/21.0f, 1.0f/21.0f, 0.5f/21.0f,
  (2.0f/3.0f+RS6)/21.0f,   1.0f/21.0f, 1.0f/21.0f, 0.5f/21.0f,
  (1.0f/3.0f+RS6)/21.0f,   1.0f/21.0f, 1.0f/21.0f, 0.5f/21.0f
};

// LDS row stride (in bf16 elements) for z and W2^T tiles. 72 = 64 + 8 pad:
// keeps 16B alignment for b128 frag reads and breaks power-of-2 bank strides.
constexpr int ZS = 72;
} // namespace

__device__ __forceinline__ unsigned short f2bf(float v) {
  unsigned u = __float_as_uint(v);
  u += 0x7fffu + ((u >> 16) & 1u);   // round-to-nearest-even
  return (unsigned short)(u >> 16);
}

__global__ __launch_bounds__(256) void gnn_mfma(
    const float* __restrict__ x,   // [G,21,2]
    const float* __restrict__ W1,  // [2,64]
    const float* __restrict__ b1,  // [64]
    const float* __restrict__ W2,  // [64,128]
    const float* __restrict__ b2,  // [128]
    float* __restrict__ out,       // [G,128]
    int G)
{
  __shared__ float sW1[128];
  __shared__ float sb1[64];
  __shared__ float sb2[128];
  __shared__ __align__(16) unsigned short w2t[128 * ZS]; // W2^T bf16: [n=128][k=64(+pad)]
  __shared__ __align__(16) unsigned short zb[64 * ZS];   // z bf16:    [g=64 ][k=64(+pad)]

  const int tid = threadIdx.x;

  // ---- stage weights: W1/b1/b2 fp32; W2 -> bf16 transposed (coalesced reads)
  if (tid < 128) { sW1[tid] = W1[tid]; sb2[tid] = b2[tid]; }
  if (tid < 64)  { sb1[tid] = b1[tid]; }
  for (int i = tid; i < 64 * 128; i += 256) {
    const int k = i >> 7, n = i & 127;
    w2t[n * ZS + k] = f2bf(W2[i]);
  }

  const int g0 = blockIdx.x * 64;
  const int gl = tid >> 2;        // graph within block (0..63)
  const int qd = tid & 3;         // feature quarter   (0..3)
  const int g  = g0 + gl;
  const bool valid = g < G;

  // ---- front-end: y = A_norm @ x[g]  (constants fold to inline literals)
  float y0[21], y1[21];
  if (valid) {
    float xs0[21], xs1[21];
    const float2* xg = (const float2*)(x + g * 42);
    #pragma unroll
    for (int t = 0; t < 21; ++t) { float2 v = xg[t]; xs0[t] = v.x; xs1[t] = v.y; }
    #pragma unroll
    for (int t = 0; t < 21; ++t) {
      float a0 = 0.f, a1 = 0.f;
      #pragma unroll
      for (int e = ROW_PTR[t]; e < ROW_PTR[t + 1]; ++e) {
        a0 = fmaf(AW[e], xs0[COL[e]], a0);
        a1 = fmaf(AW[e], xs1[COL[e]], a1);
      }
      y0[t] = a0; y1[t] = a1;
    }
  } else {
    #pragma unroll
    for (int t = 0; t < 21; ++t) { y0[t] = 0.f; y1[t] = 0.f; }
  }

  __syncthreads();   // sW1/sb1 ready

  // ---- z: this thread's 16 features (f = qd*16 + j), bf16-packed to LDS
  {
    unsigned int zp[8];
    #pragma unroll
    for (int j = 0; j < 16; ++j) {
      const int f = qd * 16 + j;
      const float u0 = sW1[f];
      const float u1 = sW1[64 + f];
      const float bv = sb1[f];
      float a = 0.f;
      #pragma unroll
      for (int t = 0; t < 21; ++t) {
        float r = fmaf(y0[t], u0, fmaf(y1[t], u1, bv));
        r = fmaxf(r, 0.f);
        a = fmaf(WPOOL[t], r, a);
      }
      const unsigned short h = f2bf(a);
      if (j & 1) zp[j >> 1] |= ((unsigned)h) << 16;
      else       zp[j >> 1]  = (unsigned)h;
    }
    uint4* zd = (uint4*)&zb[gl * ZS + qd * 16];
    zd[0] = make_uint4(zp[0], zp[1], zp[2], zp[3]);
    zd[1] = make_uint4(zp[4], zp[5], zp[6], zp[7]);
  }

  __syncthreads();   // zb + w2t ready

  // ---- phase 2: per-wave MFMA. Wave w: graphs g0 + w*16 .. +15.
  const int lane = tid & 63;
  const int w    = tid >> 6;
  const int col  = lane & 15;     // A-row m / C-col n / B-col n
  const int quad = lane >> 4;     // k-subblock selector

  // A frags: A[m][k = s*32 + quad*8 + j]  -> contiguous 8 bf16 in zb row m
  short8 afrag[2];
  #pragma unroll
  for (int s = 0; s < 2; ++s)
    afrag[s] = *(const short8*)&zb[(w * 16 + col) * ZS + s * 32 + quad * 8];

  float4v acc[8];
  #pragma unroll
  for (int nt = 0; nt < 8; ++nt) acc[nt] = (float4v){0.f, 0.f, 0.f, 0.f};

  #pragma unroll
  for (int s = 0; s < 2; ++s) {
    #pragma unroll
    for (int nt = 0; nt < 8; ++nt) {
      // B[k][n]: lane n=col holds k = s*32 + quad*8 + j  -> contiguous in w2t row
      short8 bfrag = *(const short8*)&w2t[(nt * 16 + col) * ZS + s * 32 + quad * 8];
      acc[nt] = __builtin_amdgcn_mfma_f32_16x16x32_bf16(afrag[s], bfrag, acc[nt], 0, 0, 0);
    }
  }

  // ---- epilogue: + b2, store. C layout: col = lane&15, row = quad*4 + r.
  #pragma unroll
  for (int nt = 0; nt < 8; ++nt) {
    const float bv = sb2[nt * 16 + col];
    #pragma unroll
    for (int r = 0; r < 4; ++r) {
      const int gout = g0 + w * 16 + quad * 4 + r;
      if (gout < G) out[gout * 128 + nt * 16 + col] = acc[nt][r] + bv;
    }
  }
}

extern "C" void kernel_launch(void* const* d_in, const int* in_sizes, int n_in,
                              void* d_out, int out_size, void* d_ws, size_t ws_size,
                              hipStream_t stream) {
  const float* x  = (const float*)d_in[0];
  const float* W1 = (const float*)d_in[1];
  const float* b1 = (const float*)d_in[2];
  const float* W2 = (const float*)d_in[3];
  const float* b2 = (const float*)d_in[4];
  float* out = (float*)d_out;

  const int G = in_sizes[0] / 42;
  const int blocks = (G + 63) / 64;
  hipLaunchKernelGGL(gnn_mfma, dim3(blocks), dim3(256), 0, stream,
                     x, W1, b1, W2, b2, out, G);
}

// Round 3
// 74.209 us; speedup vs baseline: 1.3125x; 1.0599x over previous
//
#include <hip/hip_runtime.h>

// HandGNNEncoder: fused GCN(2->64) + relu + GCN(64->128) + mean-pool.
// Exact algebraic rewrite:
//   y = A_norm @ x                                    (sparse, 44 nnz)
//   z = sum_t wpool[t] * relu(y[t,:] @ W1 + b1)       (64-vector / graph)
//   out = z @ W2 + b2                                  (128 / graph)
// Phase 1: VALU computes z (4 thr/graph, 64 graphs/block), packed f32
//          (v_pk_fma_f32) over feature pairs -> bf16 in LDS.
// Phase 2: per-wave MFMA 16x16x32_bf16 with A=W2^T, B=z so D=[feature][graph]:
//          lane holds 4 consecutive features of one graph -> float4 stores.

typedef __attribute__((ext_vector_type(8))) short short8;
typedef __attribute__((ext_vector_type(4))) float float4v;
typedef __attribute__((ext_vector_type(2))) float float2v;

namespace {
constexpr float RS2 = 0.70710678118654752f;
constexpr float RS3 = 0.57735026918962576f;
constexpr float RS6 = 0.40824829046386302f;
constexpr float TH  = 1.0f / 3.0f;
constexpr float HF  = 0.5f;

constexpr int ROW_PTR[22] = {0,1,3,5,7,9,11,13,15,17,20,22,24,26,29,31,33,35,38,40,42,44};
constexpr int COL[44] = {
  0,
  0,1,  1,2,  2,3,  3,4,
  0,5,  5,6,  6,7,  7,8,
  0,5,9,   9,10, 10,11, 11,12,
  0,9,13,  13,14, 14,15, 15,16,
  0,13,17, 17,18, 18,19, 19,20
};
constexpr float AW[44] = {
  1.0f,
  RS2,HF,  HF,HF,  HF,HF,  HF,HF,
  RS2,HF,  HF,HF,  HF,HF,  HF,HF,
  RS3,RS6,TH,  RS6,HF,  HF,HF,  HF,HF,
  RS3,TH,TH,   RS6,HF,  HF,HF,  HF,HF,
  RS3,TH,TH,   RS6,HF,  HF,HF,  HF,HF
};
constexpr float WPOOL[21] = {
  (1.0f + 2.0f*RS2 + 3.0f*RS3)/21.0f,
  1.0f/21.0f, 1.0f/21.0f, 1.0f/21.0f, 0.5f/21.0f,
  (1.0f+RS6)/21.0f,        1.0f/21.0f, 1.0f/21.0f, 0.5f/21.0f,
  (2.0f/3.0f+RS6)/21.0f,   1.0f/21.0f, 1.0f/21.0f, 0.5f/21.0f,
  (2.0f/3.0f+RS6)/21.0f,   1.0f/21.0f, 1.0f/21.0f, 0.5f/21.0f,
  (1.0f/3.0f+RS6)/21.0f,   1.0f/21.0f, 1.0f/21.0f, 0.5f/21.0f
};

// LDS row stride (bf16 elems) for z / W2^T tiles: 64 + 8 pad keeps 16B
// alignment for b128 frag reads and breaks power-of-2 bank strides.
constexpr int ZS = 72;
} // namespace

__device__ __forceinline__ unsigned short f2bf(float v) {
  unsigned u = __float_as_uint(v);
  u += 0x7fffu + ((u >> 16) & 1u);   // round-to-nearest-even
  return (unsigned short)(u >> 16);
}

__global__ __launch_bounds__(256) void gnn_mfma(
    const float* __restrict__ x,   // [G,21,2]
    const float* __restrict__ W1,  // [2,64]
    const float* __restrict__ b1,  // [64]
    const float* __restrict__ W2,  // [64,128]
    const float* __restrict__ b2,  // [128]
    float* __restrict__ out,       // [G,128]
    int G)
{
  __shared__ float sW1[128];
  __shared__ float sb1[64];
  __shared__ float sb2[128];
  __shared__ __align__(16) unsigned short w2t[128 * ZS]; // W2^T bf16: [n=128][k=64+pad]
  __shared__ __align__(16) unsigned short zb[64 * ZS];   // z bf16:    [g=64 ][k=64+pad]

  const int tid = threadIdx.x;

  // ---- stage weights: W1/b1/b2 fp32; W2 -> bf16 transposed (coalesced reads)
  if (tid < 128) { sW1[tid] = W1[tid]; sb2[tid] = b2[tid]; }
  if (tid < 64)  { sb1[tid] = b1[tid]; }
  for (int i = tid; i < 64 * 128; i += 256) {
    const int k = i >> 7, n = i & 127;
    w2t[n * ZS + k] = f2bf(W2[i]);
  }

  const int g0 = blockIdx.x * 64;
  const int gl = tid >> 2;        // graph within block (0..63)
  const int qd = tid & 3;         // feature quarter   (0..3)
  const int g  = g0 + gl;
  const bool valid = g < G;

  // ---- front-end: y = A_norm @ x[g]  (constants fold to inline literals)
  float y0[21], y1[21];
  if (valid) {
    float xs0[21], xs1[21];
    const float2* xg = (const float2*)(x + g * 42);
    #pragma unroll
    for (int t = 0; t < 21; ++t) { float2 v = xg[t]; xs0[t] = v.x; xs1[t] = v.y; }
    #pragma unroll
    for (int t = 0; t < 21; ++t) {
      float a0 = 0.f, a1 = 0.f;
      #pragma unroll
      for (int e = ROW_PTR[t]; e < ROW_PTR[t + 1]; ++e) {
        a0 = fmaf(AW[e], xs0[COL[e]], a0);
        a1 = fmaf(AW[e], xs1[COL[e]], a1);
      }
      y0[t] = a0; y1[t] = a1;
    }
  } else {
    #pragma unroll
    for (int t = 0; t < 21; ++t) { y0[t] = 0.f; y1[t] = 0.f; }
  }

  __syncthreads();   // sW1/sb1 ready

  // ---- z: this thread's 16 features (f = qd*16 + 2j, 2j+1), packed-f32.
  // accp[j] = {z_{2j}, z_{2j+1}} -> exactly the bf16 pack order.
  {
    float2v u0p[8], u1p[8], bvp[8], accp[8];
    #pragma unroll
    for (int j = 0; j < 8; ++j) {
      u0p[j]  = *(const float2v*)&sW1[qd * 16 + 2 * j];
      u1p[j]  = *(const float2v*)&sW1[64 + qd * 16 + 2 * j];
      bvp[j]  = *(const float2v*)&sb1[qd * 16 + 2 * j];
      accp[j] = (float2v){0.f, 0.f};
    }
    #pragma unroll
    for (int t = 0; t < 21; ++t) {
      const float2v y0b = {y0[t], y0[t]};
      const float2v y1b = {y1[t], y1[t]};
      const float2v wpb = {WPOOL[t], WPOOL[t]};
      #pragma unroll
      for (int j = 0; j < 8; ++j) {
        float2v r = __builtin_elementwise_fma(
            y0b, u0p[j], __builtin_elementwise_fma(y1b, u1p[j], bvp[j]));
        r = __builtin_elementwise_max(r, (float2v){0.f, 0.f});
        accp[j] = __builtin_elementwise_fma(wpb, r, accp[j]);
      }
    }
    unsigned int zp[8];
    #pragma unroll
    for (int j = 0; j < 8; ++j)
      zp[j] = (unsigned)f2bf(accp[j][0]) | (((unsigned)f2bf(accp[j][1])) << 16);
    uint4* zd = (uint4*)&zb[gl * ZS + qd * 16];
    zd[0] = make_uint4(zp[0], zp[1], zp[2], zp[3]);
    zd[1] = make_uint4(zp[4], zp[5], zp[6], zp[7]);
  }

  __syncthreads();   // zb + w2t ready

  // ---- phase 2: per-wave MFMA. Wave w: graphs g0 + w*16 .. +15.
  // D[m=feature][n=graph]: A = W2^T[feature][k], B = z[k][graph].
  const int lane = tid & 63;
  const int w    = tid >> 6;
  const int col  = lane & 15;     // A-row m / B-col n / D-col n
  const int quad = lane >> 4;     // k-subblock selector; D-row = quad*4+r

  // B frags: lane holds graph col's k = s*32 + quad*8 + j (contiguous in zb)
  short8 bfrag[2];
  #pragma unroll
  for (int s = 0; s < 2; ++s)
    bfrag[s] = *(const short8*)&zb[(w * 16 + col) * ZS + s * 32 + quad * 8];

  float4v acc[8];
  #pragma unroll
  for (int nt = 0; nt < 8; ++nt) acc[nt] = (float4v){0.f, 0.f, 0.f, 0.f};

  #pragma unroll
  for (int s = 0; s < 2; ++s) {
    #pragma unroll
    for (int nt = 0; nt < 8; ++nt) {
      // A[m=feature][k]: lane holds feature nt*16+col's k-run (contiguous)
      short8 afrag = *(const short8*)&w2t[(nt * 16 + col) * ZS + s * 32 + quad * 8];
      acc[nt] = __builtin_amdgcn_mfma_f32_16x16x32_bf16(afrag, bfrag[s], acc[nt], 0, 0, 0);
    }
  }

  // ---- epilogue: + b2, float4 store. D layout: col=lane&15 (graph),
  // row=quad*4+r (feature) -> lane owns 4 consecutive features of one graph.
  const int gout = g0 + w * 16 + col;
  if (gout < G) {
    #pragma unroll
    for (int nt = 0; nt < 8; ++nt) {
      const float4 bv = *(const float4*)&sb2[nt * 16 + quad * 4];
      float4 v = make_float4(acc[nt][0] + bv.x, acc[nt][1] + bv.y,
                             acc[nt][2] + bv.z, acc[nt][3] + bv.w);
      *(float4*)&out[gout * 128 + nt * 16 + quad * 4] = v;
    }
  }
}

extern "C" void kernel_launch(void* const* d_in, const int* in_sizes, int n_in,
                              void* d_out, int out_size, void* d_ws, size_t ws_size,
                              hipStream_t stream) {
  const float* x  = (const float*)d_in[0];
  const float* W1 = (const float*)d_in[1];
  const float* b1 = (const float*)d_in[2];
  const float* W2 = (const float*)d_in[3];
  const float* b2 = (const float*)d_in[4];
  float* out = (float*)d_out;

  const int G = in_sizes[0] / 42;
  const int blocks = (G + 63) / 64;
  hipLaunchKernelGGL(gnn_mfma, dim3(blocks), dim3(256), 0, stream,
                     x, W1, b1, W2, b2, out, G);
}

// Round 4
// 74.074 us; speedup vs baseline: 1.3149x; 1.0018x over previous
//
#include <hip/hip_runtime.h>

// HandGNNEncoder: fused GCN(2->64) + relu + GCN(64->128) + mean-pool.
// Exact algebraic rewrite:
//   y = A_norm @ x                                    (sparse, 44 nnz)
//   z = sum_t wpool[t] * relu(y[t,:] @ W1 + b1)       (64-vector / graph)
//   out = z @ W2 + b2                                  (128 / graph)
// Phase 1: x loads issued FIRST (HBM latency drains behind W2 staging),
//          front-end + z-loop in packed f32 (v_pk_fma_f32) -> bf16 in LDS.
// Phase 2: per-wave MFMA 16x16x32_bf16 with A=W2^T, B=z so D=[feature][graph]:
//          lane holds 4 consecutive features of one graph -> float4 stores.

typedef __attribute__((ext_vector_type(8))) short short8;
typedef __attribute__((ext_vector_type(4))) float float4v;
typedef __attribute__((ext_vector_type(2))) float float2v;

namespace {
constexpr float RS2 = 0.70710678118654752f;
constexpr float RS3 = 0.57735026918962576f;
constexpr float RS6 = 0.40824829046386302f;
constexpr float TH  = 1.0f / 3.0f;
constexpr float HF  = 0.5f;

constexpr int ROW_PTR[22] = {0,1,3,5,7,9,11,13,15,17,20,22,24,26,29,31,33,35,38,40,42,44};
constexpr int COL[44] = {
  0,
  0,1,  1,2,  2,3,  3,4,
  0,5,  5,6,  6,7,  7,8,
  0,5,9,   9,10, 10,11, 11,12,
  0,9,13,  13,14, 14,15, 15,16,
  0,13,17, 17,18, 18,19, 19,20
};
constexpr float AW[44] = {
  1.0f,
  RS2,HF,  HF,HF,  HF,HF,  HF,HF,
  RS2,HF,  HF,HF,  HF,HF,  HF,HF,
  RS3,RS6,TH,  RS6,HF,  HF,HF,  HF,HF,
  RS3,TH,TH,   RS6,HF,  HF,HF,  HF,HF,
  RS3,TH,TH,   RS6,HF,  HF,HF,  HF,HF
};
constexpr float WPOOL[21] = {
  (1.0f + 2.0f*RS2 + 3.0f*RS3)/21.0f,
  1.0f/21.0f, 1.0f/21.0f, 1.0f/21.0f, 0.5f/21.0f,
  (1.0f+RS6)/21.0f,        1.0f/21.0f, 1.0f/21.0f, 0.5f/21.0f,
  (2.0f/3.0f+RS6)/21.0f,   1.0f/21.0f, 1.0f/21.0f, 0.5f/21.0f,
  (2.0f/3.0f+RS6)/21.0f,   1.0f/21.0f, 1.0f/21.0f, 0.5f/21.0f,
  (1.0f/3.0f+RS6)/21.0f,   1.0f/21.0f, 1.0f/21.0f, 0.5f/21.0f
};

// LDS row stride (bf16 elems): 64 + 8 pad keeps 16B alignment (144 B = 9*16)
// for b128 frag reads and breaks power-of-2 bank strides.
constexpr int ZS = 72;
} // namespace

__device__ __forceinline__ unsigned short f2bf(float v) {
  unsigned u = __float_as_uint(v);
  u += 0x7fffu + ((u >> 16) & 1u);   // round-to-nearest-even
  return (unsigned short)(u >> 16);
}

__global__ __launch_bounds__(256) void gnn_mfma(
    const float* __restrict__ x,   // [G,21,2]
    const float* __restrict__ W1,  // [2,64]
    const float* __restrict__ b1,  // [64]
    const float* __restrict__ W2,  // [64,128]
    const float* __restrict__ b2,  // [128]
    float* __restrict__ out,       // [G,128]
    int G)
{
  __shared__ float sW1[128];
  __shared__ float sb1[64];
  __shared__ float sb2[128];
  __shared__ __align__(16) unsigned short w2t[128 * ZS]; // W2^T bf16: [n=128][k=64+pad]
  __shared__ __align__(16) unsigned short zb[64 * ZS];   // z bf16:    [g=64 ][k=64+pad]

  const int tid = threadIdx.x;
  const int g0 = blockIdx.x * 64;
  const int gl = tid >> 2;        // graph within block (0..63)
  const int qd = tid & 3;         // feature quarter   (0..3)
  const int g  = g0 + gl;
  const bool valid = g < G;

  // ---- issue x loads FIRST: their HBM latency drains behind W2 staging.
  float2v xs[21];
  if (valid) {
    const float2* xg = (const float2*)(x + g * 42);
    #pragma unroll
    for (int t = 0; t < 21; ++t) {
      float2 v = xg[t];
      xs[t] = (float2v){v.x, v.y};
    }
  } else {
    #pragma unroll
    for (int t = 0; t < 21; ++t) xs[t] = (float2v){0.f, 0.f};
  }

  // ---- stage weights. W2 -> bf16 transposed; thread owns (n, k-half):
  // 32 coalesced dword loads, 4 b128 LDS writes.
  if (tid < 128) { sW1[tid] = W1[tid]; sb2[tid] = b2[tid]; }
  if (tid < 64)  { sb1[tid] = b1[tid]; }
  {
    const int n  = tid & 127;
    const int k0 = (tid >> 7) * 32;
    unsigned int wp[16];
    #pragma unroll
    for (int r = 0; r < 16; ++r) {
      const float v0 = W2[(k0 + 2 * r) * 128 + n];
      const float v1 = W2[(k0 + 2 * r + 1) * 128 + n];
      wp[r] = (unsigned)f2bf(v0) | (((unsigned)f2bf(v1)) << 16);
    }
    uint4* wd = (uint4*)&w2t[n * ZS + k0];
    wd[0] = make_uint4(wp[0],  wp[1],  wp[2],  wp[3]);
    wd[1] = make_uint4(wp[4],  wp[5],  wp[6],  wp[7]);
    wd[2] = make_uint4(wp[8],  wp[9],  wp[10], wp[11]);
    wd[3] = make_uint4(wp[12], wp[13], wp[14], wp[15]);
  }

  // ---- front-end: y = A_norm @ x[g], packed over (x,y) coords. 44 pk_fma.
  float2v y[21];
  #pragma unroll
  for (int t = 0; t < 21; ++t) {
    float2v a = (float2v){0.f, 0.f};
    #pragma unroll
    for (int e = ROW_PTR[t]; e < ROW_PTR[t + 1]; ++e) {
      const float2v aw = {AW[e], AW[e]};
      a = __builtin_elementwise_fma(aw, xs[COL[e]], a);
    }
    y[t] = a;
  }

  __syncthreads();   // sW1/sb1 ready

  // ---- z: this thread's 16 features (f = qd*16 + 2j, 2j+1), packed-f32.
  // accp[j] = {z_{2j}, z_{2j+1}} -> exactly the bf16 pack order.
  {
    float2v u0p[8], u1p[8], bvp[8], accp[8];
    #pragma unroll
    for (int j = 0; j < 8; ++j) {
      u0p[j]  = *(const float2v*)&sW1[qd * 16 + 2 * j];
      u1p[j]  = *(const float2v*)&sW1[64 + qd * 16 + 2 * j];
      bvp[j]  = *(const float2v*)&sb1[qd * 16 + 2 * j];
      accp[j] = (float2v){0.f, 0.f};
    }
    #pragma unroll
    for (int t = 0; t < 21; ++t) {
      const float2v y0b = {y[t][0], y[t][0]};
      const float2v y1b = {y[t][1], y[t][1]};
      const float2v wpb = {WPOOL[t], WPOOL[t]};
      #pragma unroll
      for (int j = 0; j < 8; ++j) {
        float2v r = __builtin_elementwise_fma(
            y0b, u0p[j], __builtin_elementwise_fma(y1b, u1p[j], bvp[j]));
        r = __builtin_elementwise_max(r, (float2v){0.f, 0.f});
        accp[j] = __builtin_elementwise_fma(wpb, r, accp[j]);
      }
    }
    unsigned int zp[8];
    #pragma unroll
    for (int j = 0; j < 8; ++j)
      zp[j] = (unsigned)f2bf(accp[j][0]) | (((unsigned)f2bf(accp[j][1])) << 16);
    uint4* zd = (uint4*)&zb[gl * ZS + qd * 16];
    zd[0] = make_uint4(zp[0], zp[1], zp[2], zp[3]);
    zd[1] = make_uint4(zp[4], zp[5], zp[6], zp[7]);
  }

  __syncthreads();   // zb + w2t ready

  // ---- phase 2: per-wave MFMA. Wave w: graphs g0 + w*16 .. +15.
  // D[m=feature][n=graph]: A = W2^T[feature][k], B = z[k][graph].
  const int lane = tid & 63;
  const int w    = tid >> 6;
  const int col  = lane & 15;     // A-row m / B-col n / D-col n
  const int quad = lane >> 4;     // k-subblock selector; D-row = quad*4+r

  short8 bfrag[2];
  #pragma unroll
  for (int s = 0; s < 2; ++s)
    bfrag[s] = *(const short8*)&zb[(w * 16 + col) * ZS + s * 32 + quad * 8];

  float4v acc[8];
  #pragma unroll
  for (int nt = 0; nt < 8; ++nt) acc[nt] = (float4v){0.f, 0.f, 0.f, 0.f};

  #pragma unroll
  for (int s = 0; s < 2; ++s) {
    #pragma unroll
    for (int nt = 0; nt < 8; ++nt) {
      short8 afrag = *(const short8*)&w2t[(nt * 16 + col) * ZS + s * 32 + quad * 8];
      acc[nt] = __builtin_amdgcn_mfma_f32_16x16x32_bf16(afrag, bfrag[s], acc[nt], 0, 0, 0);
    }
  }

  // ---- epilogue: + b2, float4 store. D layout: col=lane&15 (graph),
  // row=quad*4+r (feature) -> lane owns 4 consecutive features of one graph.
  const int gout = g0 + w * 16 + col;
  if (gout < G) {
    #pragma unroll
    for (int nt = 0; nt < 8; ++nt) {
      const float4 bv = *(const float4*)&sb2[nt * 16 + quad * 4];
      float4 v = make_float4(acc[nt][0] + bv.x, acc[nt][1] + bv.y,
                             acc[nt][2] + bv.z, acc[nt][3] + bv.w);
      *(float4*)&out[gout * 128 + nt * 16 + quad * 4] = v;
    }
  }
}

extern "C" void kernel_launch(void* const* d_in, const int* in_sizes, int n_in,
                              void* d_out, int out_size, void* d_ws, size_t ws_size,
                              hipStream_t stream) {
  const float* x  = (const float*)d_in[0];
  const float* W1 = (const float*)d_in[1];
  const float* b1 = (const float*)d_in[2];
  const float* W2 = (const float*)d_in[3];
  const float* b2 = (const float*)d_in[4];
  float* out = (float*)d_out;

  const int G = in_sizes[0] / 42;
  const int blocks = (G + 63) / 64;
  hipLaunchKernelGGL(gnn_mfma, dim3(blocks), dim3(256), 0, stream,
                     x, W1, b1, W2, b2, out, G);
}